// Round 1
// 242.057 us; speedup vs baseline: 1.0048x; 1.0048x over previous
//
#include <hip/hip_runtime.h>
#include <stdint.h>

// Problem constants: B=4, Q=2048, K=2048, D=1024 (fp32 in/out, int32 mask)
#define BB 4
#define QQ 2048
#define KK 2048
#define DD 1024

// ---------- helpers ----------
__device__ inline unsigned short f2bf(float f) {
    unsigned int u = __float_as_uint(f);
    unsigned int r = (u + 0x7fffu + ((u >> 16) & 1u)) >> 16;
    return (unsigned short)r;
}

typedef short bf16x8 __attribute__((ext_vector_type(8)));
typedef float f32x4  __attribute__((ext_vector_type(4)));

__device__ inline void async16(const void* g, void* l) {
    __builtin_amdgcn_global_load_lds(
        (const __attribute__((address_space(1))) unsigned int*)g,
        (__attribute__((address_space(3))) unsigned int*)l,
        16, 0, 0);
}

// ---------- kernel T: value (B,K,D) fp32 -> Vt (B,D,K) bf16, tiled transpose,
// FUSED with partial row sums: s[b,k] += sum_d(tile) via one atomicAdd per row
// per tile (64/block). Replaces the old separate rowexp kernel (saves a full
// 32 MB read of V and one dispatch). exp() moved into weights_k.
__global__ __launch_bounds__(256) void transpose_sum(const float* __restrict__ V,
                                                     unsigned short* __restrict__ Vt,
                                                     float* __restrict__ s) {
    int bid = blockIdx.x;
    int b  = bid >> 9;        // 512 tiles per batch (32 k-tiles x 16 d-tiles)
    int r  = bid & 511;
    int kt = r >> 4;
    int dt = r & 15;
    int k0 = kt * 64, d0 = dt * 64;
    __shared__ float tile[64 * 65];
    int t = threadIdx.x;
    for (int i = 0; i < 4; i++) {
        int idx = i * 256 + t;
        int row = idx >> 4;   // k offset in tile
        int c4  = idx & 15;   // d group of 4
        float4 v = *(const float4*)(V + (size_t)(b * KK + k0 + row) * DD + d0 + c4 * 4);
        float* p = &tile[row * 65 + c4 * 4];
        p[0] = v.x; p[1] = v.y; p[2] = v.z; p[3] = v.w;
        // partial row sum over this tile's 64 d-columns (16 consecutive lanes per row)
        float ps = (v.x + v.y) + (v.z + v.w);
        ps += __shfl_xor(ps, 8, 16);
        ps += __shfl_xor(ps, 4, 16);
        ps += __shfl_xor(ps, 2, 16);
        ps += __shfl_xor(ps, 1, 16);
        if (c4 == 0) atomicAdd(s + (size_t)b * KK + k0 + row, ps);
    }
    __syncthreads();
    for (int i = 0; i < 4; i++) {
        int idx = i * 256 + t;
        int dr = idx >> 4;    // d offset in tile
        int kc = idx & 15;    // k group of 4
        ushort4 o;
        o.x = f2bf(tile[(kc * 4 + 0) * 65 + dr]);
        o.y = f2bf(tile[(kc * 4 + 1) * 65 + dr]);
        o.z = f2bf(tile[(kc * 4 + 2) * 65 + dr]);
        o.w = f2bf(tile[(kc * 4 + 3) * 65 + dr]);
        *(ushort4*)(Vt + (size_t)(b * DD + d0 + dr) * KK + k0 + kc * 4) = o;
    }
}

// ---------- kernel W: one WAVE per (b,q) row: masked softmax weights (no barriers).
// e[k] = exp(s[k]/32) computed inline (4 __expf per 16B loaded — hidden under BW).
// No max-shift: rowsum/32 ~ N(0,1), exp in [~.03,~60] — fp32-safe, softmax shift-invariant.
__global__ __launch_bounds__(256) void weights_k(const int* __restrict__ mask,
                                                 const float* __restrict__ s,
                                                 float* __restrict__ wout,
                                                 unsigned short* __restrict__ wb16) {
    int wave = threadIdx.x >> 6, lane = threadIdx.x & 63;
    int row = blockIdx.x * 4 + wave;     // b*Q + q
    int b = row >> 11;
    const int4*   mp = (const int4*)(mask + (size_t)row * KK);
    const float4* ep = (const float4*)(s + (size_t)b * KK);
    float4 w[8];
    float ss = 0.f;
    for (int j = 0; j < 8; j++) {
        int4   m  = mp[lane + j * 64];
        float4 sv = ep[lane + j * 64];
        float4 ev;
        ev.x = __expf(sv.x * 0.03125f);   // 1/sqrt(1024) = 1/32
        ev.y = __expf(sv.y * 0.03125f);
        ev.z = __expf(sv.z * 0.03125f);
        ev.w = __expf(sv.w * 0.03125f);
        w[j].x = m.x ? ev.x : 0.f;
        w[j].y = m.y ? ev.y : 0.f;
        w[j].z = m.z ? ev.z : 0.f;
        w[j].w = m.w ? ev.w : 0.f;
        ss += (w[j].x + w[j].y) + (w[j].z + w[j].w);
    }
    for (int off = 32; off; off >>= 1) ss += __shfl_xor(ss, off, 64);
    float rS = 1.f / ss;
    float4*  wp = (float4*)(wout + (size_t)row * KK);
    ushort4* bp = (ushort4*)(wb16 + (size_t)row * KK);
    for (int j = 0; j < 8; j++) {
        float4 v = w[j];
        v.x *= rS; v.y *= rS; v.z *= rS; v.w *= rS;
        wp[lane + j * 64] = v;
        ushort4 pk;
        pk.x = f2bf(v.x); pk.y = f2bf(v.y); pk.z = f2bf(v.z); pk.w = f2bf(v.w);
        bp[lane + j * 64] = pk;
    }
}

// ---------- kernel G: context[b] = W[b] (Q x K) @ V[b]^T, bf16 MFMA ----------
// 128x128 tile, BK=64 (32 iters), 4 waves (2x2), each wave 4x4 of 16x16x32 over 2 k-halves.
// Grid 512 = 2 blocks/CU. XCD mapping: bid = dt*64 + b*16 + qt (A-tile shared per XCD).
// XOR chunk swizzle (chunk ^ row&7, 128 B row stride) keeps async16 lane*16 contiguity
// AND makes ds_read_b128 conflict-free.
// NEW (this round): double-buffered LDS + 2-phase prefetch schedule (T3-minimum):
// issue STAGE(t+1 -> other buf) BEFORE compute(t); single counted drain
// (vmcnt(0) lgkmcnt(0), pinned by sched_barrier(0)) + raw s_barrier per tile.
// Global-load latency now hides under the 32-MFMA cluster instead of being
// drained cold at a __syncthreads (the m196-V0 stall).
__global__ __launch_bounds__(256) void gemm_ctx(const unsigned short* __restrict__ Wb,
                                                const unsigned short* __restrict__ Vt,
                                                float* __restrict__ ctx) {
    int bid = blockIdx.x;
    int dt = bid >> 6;          // 0..7
    int b  = (bid >> 4) & 3;
    int qt = bid & 15;
    int q0 = qt * 128, n0 = dt * 128;
    __shared__ unsigned short As[2][128 * 64];   // [buf][m][k], 2x16 KB
    __shared__ unsigned short Bs[2][128 * 64];   // [buf][n][k], 2x16 KB
    int tid = threadIdx.x, wave = tid >> 6, lane = tid & 63;
    int quad = lane >> 4, lm = lane & 15;
    int wm = wave >> 1, wn = wave & 1;

    // staging: per async16 instr, a wave covers 8 rows x 64 k (1 KB), dst = base + lane*16
    int srow   = lane >> 3;                 // row within 8-row group
    int schunk = (lane & 7) ^ srow;         // XOR-swizzled source chunk (16B units)
    const unsigned short* Ag = Wb + (size_t)(b * QQ + q0 + wave * 8 + srow) * KK + schunk * 8;
    const unsigned short* Bg = Vt + (size_t)(b * DD + n0 + wave * 8 + srow) * KK + schunk * 8;
    unsigned short* lA0 = &As[0][(wave * 8) * 64];
    unsigned short* lA1 = &As[1][(wave * 8) * 64];
    unsigned short* lB0 = &Bs[0][(wave * 8) * 64];
    unsigned short* lB1 = &Bs[1][(wave * 8) * 64];

    // fragment LDS offsets (ushort units): row (.. + lm), k-chunk (h*4+quad) ^ (lm&7)
    int m7 = lm & 7;
    int xa0 = lm * 64 + ((0 + quad) ^ m7) * 8;   // h=0
    int xa1 = lm * 64 + ((4 + quad) ^ m7) * 8;   // h=1

    f32x4 acc[4][4];
    for (int i = 0; i < 4; i++)
        for (int j = 0; j < 4; j++) acc[i][j] = 0.f;

#define STAGE(dA, dB, kpos) do {                                           \
        for (int c = 0; c < 4; c++) {                                      \
            async16(Ag + (size_t)(c * 32) * KK + (kpos), (dA) + c * 32 * 64); \
            async16(Bg + (size_t)(c * 32) * KK + (kpos), (dB) + c * 32 * 64); \
        }                                                                  \
    } while (0)

#define COMPUTE(Ab, Bb) do {                                               \
        bf16x8 a[4][2], bv[4][2];                                          \
        for (int i = 0; i < 4; i++) {                                      \
            a[i][0]  = *(const bf16x8*)&(Ab)[(wm * 64 + i * 16) * 64 + xa0]; \
            a[i][1]  = *(const bf16x8*)&(Ab)[(wm * 64 + i * 16) * 64 + xa1]; \
            bv[i][0] = *(const bf16x8*)&(Bb)[(wn * 64 + i * 16) * 64 + xa0]; \
            bv[i][1] = *(const bf16x8*)&(Bb)[(wn * 64 + i * 16) * 64 + xa1]; \
        }                                                                  \
        for (int h = 0; h < 2; h++)                                        \
            for (int i = 0; i < 4; i++)                                    \
                for (int j = 0; j < 4; j++)                                \
                    acc[i][j] = __builtin_amdgcn_mfma_f32_16x16x32_bf16(   \
                        a[i][h], bv[j][h], acc[i][j], 0, 0, 0);            \
    } while (0)

#define DRAIN_BARRIER() do {                                               \
        __builtin_amdgcn_sched_barrier(0);                                 \
        asm volatile("s_waitcnt vmcnt(0) lgkmcnt(0)" ::: "memory");        \
        __builtin_amdgcn_s_barrier();                                      \
    } while (0)

    // prologue: fill buf0 with tile 0
    STAGE(lA0, lB0, 0);
    DRAIN_BARRIER();

    for (int t = 0; t < 32; t += 2) {
        // even phase: prefetch tile t+1 into buf1, compute tile t from buf0
        STAGE(lA1, lB1, (t + 1) * 64);
        COMPUTE(&As[0][0], &Bs[0][0]);
        DRAIN_BARRIER();
        // odd phase: prefetch tile t+2 into buf0 (if any), compute t+1 from buf1
        if (t + 2 < 32) STAGE(lA0, lB0, (t + 2) * 64);
        COMPUTE(&As[1][0], &Bs[1][0]);
        if (t + 2 < 32) DRAIN_BARRIER();
    }

#undef STAGE
#undef COMPUTE
#undef DRAIN_BARRIER

    // epilogue: C row = quad*4 + reg, col = lane&15 (m89-verified layout)
    for (int i = 0; i < 4; i++) {
        int rowb = q0 + wm * 64 + i * 16 + quad * 4;
        for (int j = 0; j < 4; j++) {
            int col = n0 + wn * 64 + j * 16 + lm;
            for (int rr = 0; rr < 4; rr++)
                ctx[(size_t)(b * QQ + rowb + rr) * DD + col] = acc[i][j][rr];
        }
    }
}

extern "C" void kernel_launch(void* const* d_in, const int* in_sizes, int n_in,
                              void* d_out, int out_size, void* d_ws, size_t ws_size,
                              hipStream_t stream) {
    // inputs: query (unused — cancels in softmax), value, attention_mask
    const float* value = (const float*)d_in[1];
    const int*   mask  = (const int*)d_in[2];
    float* out = (float*)d_out;

    // workspace layout (~48.03 MB):
    unsigned short* Vt = (unsigned short*)d_ws;                       // B*D*K bf16 = 16 MB
    unsigned short* Wb = Vt + (size_t)BB * DD * KK;                   // B*Q*K bf16 = 32 MB
    float* s = (float*)(Wb + (size_t)BB * QQ * KK);                   // B*K fp32 raw row sums

    float* ctx  = out;                              // (B,Q,D)
    float* wout = out + (size_t)BB * QQ * DD;       // (B,Q,K)

    hipMemsetAsync(s, 0, (size_t)BB * KK * sizeof(float), stream);
    transpose_sum<<<BB * 512, 256, 0, stream>>>(value, Vt, s);
    weights_k<<<(BB * QQ) / 4, 256, 0, stream>>>(mask, s, wout, Wb);
    gemm_ctx<<<BB * 128, 256, 0, stream>>>(Wb, Vt, ctx);
}

// Round 2
// 240.088 us; speedup vs baseline: 1.0130x; 1.0082x over previous
//
#include <hip/hip_runtime.h>
#include <stdint.h>

// Problem constants: B=4, Q=2048, K=2048, D=1024 (fp32 in/out, int32 mask)
#define BB 4
#define QQ 2048
#define KK 2048
#define DD 1024

// ---------- helpers ----------
__device__ inline unsigned short f2bf(float f) {
    unsigned int u = __float_as_uint(f);
    unsigned int r = (u + 0x7fffu + ((u >> 16) & 1u)) >> 16;
    return (unsigned short)r;
}

typedef short bf16x8 __attribute__((ext_vector_type(8)));
typedef float f32x4  __attribute__((ext_vector_type(4)));

__device__ inline void async16(const void* g, void* l) {
    __builtin_amdgcn_global_load_lds(
        (const __attribute__((address_space(1))) unsigned int*)g,
        (__attribute__((address_space(3))) unsigned int*)l,
        16, 0, 0);
}

// ---------- kernel T: value (B,K,D) fp32 -> Vt (B,D,K) bf16, tiled transpose,
// FUSED with partial row sums: s[b,k] += sum_d(tile) via one atomicAdd per row
// per tile (64/block).
__global__ __launch_bounds__(256) void transpose_sum(const float* __restrict__ V,
                                                     unsigned short* __restrict__ Vt,
                                                     float* __restrict__ s) {
    int bid = blockIdx.x;
    int b  = bid >> 9;        // 512 tiles per batch (32 k-tiles x 16 d-tiles)
    int r  = bid & 511;
    int kt = r >> 4;
    int dt = r & 15;
    int k0 = kt * 64, d0 = dt * 64;
    __shared__ float tile[64 * 65];
    int t = threadIdx.x;
    for (int i = 0; i < 4; i++) {
        int idx = i * 256 + t;
        int row = idx >> 4;   // k offset in tile
        int c4  = idx & 15;   // d group of 4
        float4 v = *(const float4*)(V + (size_t)(b * KK + k0 + row) * DD + d0 + c4 * 4);
        float* p = &tile[row * 65 + c4 * 4];
        p[0] = v.x; p[1] = v.y; p[2] = v.z; p[3] = v.w;
        // partial row sum over this tile's 64 d-columns (16 consecutive lanes per row)
        float ps = (v.x + v.y) + (v.z + v.w);
        ps += __shfl_xor(ps, 8, 16);
        ps += __shfl_xor(ps, 4, 16);
        ps += __shfl_xor(ps, 2, 16);
        ps += __shfl_xor(ps, 1, 16);
        if (c4 == 0) atomicAdd(s + (size_t)b * KK + k0 + row, ps);
    }
    __syncthreads();
    for (int i = 0; i < 4; i++) {
        int idx = i * 256 + t;
        int dr = idx >> 4;    // d offset in tile
        int kc = idx & 15;    // k group of 4
        ushort4 o;
        o.x = f2bf(tile[(kc * 4 + 0) * 65 + dr]);
        o.y = f2bf(tile[(kc * 4 + 1) * 65 + dr]);
        o.z = f2bf(tile[(kc * 4 + 2) * 65 + dr]);
        o.w = f2bf(tile[(kc * 4 + 3) * 65 + dr]);
        *(ushort4*)(Vt + (size_t)(b * DD + d0 + dr) * KK + k0 + kc * 4) = o;
    }
}

// ---------- kernel W: one WAVE per (b,q) row: masked softmax weights (no barriers).
// e[k] = exp(s[k]/32) computed inline. No max-shift: rowsum/32 ~ N(0,1),
// exp in [~.03,~60] — fp32-safe, softmax shift-invariant.
__global__ __launch_bounds__(256) void weights_k(const int* __restrict__ mask,
                                                 const float* __restrict__ s,
                                                 float* __restrict__ wout,
                                                 unsigned short* __restrict__ wb16) {
    int wave = threadIdx.x >> 6, lane = threadIdx.x & 63;
    int row = blockIdx.x * 4 + wave;     // b*Q + q
    int b = row >> 11;
    const int4*   mp = (const int4*)(mask + (size_t)row * KK);
    const float4* ep = (const float4*)(s + (size_t)b * KK);
    float4 w[8];
    float ss = 0.f;
    for (int j = 0; j < 8; j++) {
        int4   m  = mp[lane + j * 64];
        float4 sv = ep[lane + j * 64];
        float4 ev;
        ev.x = __expf(sv.x * 0.03125f);   // 1/sqrt(1024) = 1/32
        ev.y = __expf(sv.y * 0.03125f);
        ev.z = __expf(sv.z * 0.03125f);
        ev.w = __expf(sv.w * 0.03125f);
        w[j].x = m.x ? ev.x : 0.f;
        w[j].y = m.y ? ev.y : 0.f;
        w[j].z = m.z ? ev.z : 0.f;
        w[j].w = m.w ? ev.w : 0.f;
        ss += (w[j].x + w[j].y) + (w[j].z + w[j].w);
    }
    for (int off = 32; off; off >>= 1) ss += __shfl_xor(ss, off, 64);
    float rS = 1.f / ss;
    float4*  wp = (float4*)(wout + (size_t)row * KK);
    ushort4* bp = (ushort4*)(wb16 + (size_t)row * KK);
    for (int j = 0; j < 8; j++) {
        float4 v = w[j];
        v.x *= rS; v.y *= rS; v.z *= rS; v.w *= rS;
        wp[lane + j * 64] = v;
        ushort4 pk;
        pk.x = f2bf(v.x); pk.y = f2bf(v.y); pk.z = f2bf(v.z); pk.w = f2bf(v.w);
        bp[lane + j * 64] = pk;
    }
}

// ---------- kernel G: context[b] = W[b] (Q x K) @ V[b]^T, bf16 MFMA ----------
// 128x128 tile, BK=64 (32 iters), 4 waves (2x2), each wave 4x4 of 16x16x32 over 2 k-halves.
// Grid 512 = 2 blocks/CU. XCD mapping: bid = dt*64 + b*16 + qt (A-tile shared per XCD).
// XOR chunk swizzle (chunk ^ row&7, 128 B row stride): async16 lane*16 contiguity
// AND conflict-free ds_read_b128.
// NEW (this round): COUNTED-vmcnt 2.5-phase pipeline (T4):
//   A double-buffered (L2-resident, ~200 cyc — one compute phase covers it),
//   B TRIPLE-buffered (LLC/HBM, ~450-900 cyc — needs ~2 compute phases).
// Steady state: issue A(t+1) then B(t+2); compute(t); s_waitcnt vmcnt(4)
// (retires B(t+1)+A(t+1), leaves B(t+2) in flight ACROSS the barrier — never
// drains to 0, the m218/T4 lever); one raw s_barrier per iter.
// LDS = 2x16 (A) + 3x16 (B) = 80 KB -> still 2 blocks/CU.
// WAR safety: stage at iter t overwrites only buffers whose readers finished
// before the previous barrier (A: compute(t-1) read bA[(t-1)&1]; B: compute(t-1)
// read bB[(t-1)%3] = bB[(t+2)%3]).
__global__ __launch_bounds__(256) void gemm_ctx(const unsigned short* __restrict__ Wb,
                                                const unsigned short* __restrict__ Vt,
                                                float* __restrict__ ctx) {
    int bid = blockIdx.x;
    int dt = bid >> 6;          // 0..7
    int b  = (bid >> 4) & 3;
    int qt = bid & 15;
    int q0 = qt * 128, n0 = dt * 128;
    __shared__ unsigned short As[2][128 * 64];   // [buf][m][k], 2x16 KB
    __shared__ unsigned short Bs[3][128 * 64];   // [buf][n][k], 3x16 KB
    int tid = threadIdx.x, wave = tid >> 6, lane = tid & 63;
    int quad = lane >> 4, lm = lane & 15;
    int wm = wave >> 1, wn = wave & 1;

    // staging: per async16 instr, a wave covers 8 rows x 64 k (1 KB), dst = base + lane*16
    int srow   = lane >> 3;                 // row within 8-row group
    int schunk = (lane & 7) ^ srow;         // XOR-swizzled source chunk (16B units)
    const unsigned short* Ag = Wb + (size_t)(b * QQ + q0 + wave * 8 + srow) * KK + schunk * 8;
    const unsigned short* Bg = Vt + (size_t)(b * DD + n0 + wave * 8 + srow) * KK + schunk * 8;

    // fragment LDS offsets (ushort units): row (.. + lm), k-chunk (h*4+quad) ^ (lm&7)
    int m7 = lm & 7;
    int xa0 = lm * 64 + ((0 + quad) ^ m7) * 8;   // h=0
    int xa1 = lm * 64 + ((4 + quad) ^ m7) * 8;   // h=1

    f32x4 acc[4][4];
    for (int i = 0; i < 4; i++)
        for (int j = 0; j < 4; j++) acc[i][j] = 0.f;

#define STAGE_A(buf, kpos) do {                                               \
        unsigned short* d = &As[buf][(wave * 8) * 64];                        \
        for (int c = 0; c < 4; c++)                                           \
            async16(Ag + (size_t)(c * 32) * KK + (kpos), d + c * 32 * 64);    \
    } while (0)

#define STAGE_B(buf, kpos) do {                                               \
        unsigned short* d = &Bs[buf][(wave * 8) * 64];                        \
        for (int c = 0; c < 4; c++)                                           \
            async16(Bg + (size_t)(c * 32) * KK + (kpos), d + c * 32 * 64);    \
    } while (0)

#define COMPUTE(ab, bb) do {                                                  \
        bf16x8 a[4][2], bv[4][2];                                             \
        for (int i = 0; i < 4; i++) {                                         \
            a[i][0]  = *(const bf16x8*)&As[ab][(wm * 64 + i * 16) * 64 + xa0]; \
            a[i][1]  = *(const bf16x8*)&As[ab][(wm * 64 + i * 16) * 64 + xa1]; \
            bv[i][0] = *(const bf16x8*)&Bs[bb][(wn * 64 + i * 16) * 64 + xa0]; \
            bv[i][1] = *(const bf16x8*)&Bs[bb][(wn * 64 + i * 16) * 64 + xa1]; \
        }                                                                     \
        for (int h = 0; h < 2; h++)                                           \
            for (int i = 0; i < 4; i++)                                       \
                for (int j = 0; j < 4; j++)                                   \
                    acc[i][j] = __builtin_amdgcn_mfma_f32_16x16x32_bf16(      \
                        a[i][h], bv[j][h], acc[i][j], 0, 0, 0);               \
    } while (0)

    // prologue: A(0)->bA0, B(0)->bB0, B(1)->bB1; wait for A0,B0 (B1 stays in flight)
    STAGE_A(0, 0);
    STAGE_B(0, 0);
    STAGE_B(1, 64);
    __builtin_amdgcn_sched_barrier(0);
    asm volatile("s_waitcnt vmcnt(4)" ::: "memory");
    __builtin_amdgcn_s_barrier();

#pragma unroll
    for (int t = 0; t < 32; ++t) {
        if (t + 1 < 32) STAGE_A((t + 1) & 1, (t + 1) * 64);
        if (t + 2 < 32) STAGE_B((t + 2) % 3, (t + 2) * 64);
        COMPUTE(t & 1, t % 3);
        if (t + 1 < 32) {
            __builtin_amdgcn_sched_barrier(0);
            if (t + 2 < 32) {
                // queue: [B(t+1):4, A(t+1):4, B(t+2):4] -> retire oldest 8
                asm volatile("s_waitcnt vmcnt(4)" ::: "memory");
            } else {
                // tail (t=30): queue [B(31):4, A(31):4] -> need both
                asm volatile("s_waitcnt vmcnt(0)" ::: "memory");
            }
            __builtin_amdgcn_sched_barrier(0);
            __builtin_amdgcn_s_barrier();
        }
    }

#undef STAGE_A
#undef STAGE_B
#undef COMPUTE

    // epilogue: C row = quad*4 + reg, col = lane&15 (m89-verified layout)
    for (int i = 0; i < 4; i++) {
        int rowb = q0 + wm * 64 + i * 16 + quad * 4;
        for (int j = 0; j < 4; j++) {
            int col = n0 + wn * 64 + j * 16 + lm;
            for (int rr = 0; rr < 4; rr++)
                ctx[(size_t)(b * QQ + rowb + rr) * DD + col] = acc[i][j][rr];
        }
    }
}

extern "C" void kernel_launch(void* const* d_in, const int* in_sizes, int n_in,
                              void* d_out, int out_size, void* d_ws, size_t ws_size,
                              hipStream_t stream) {
    // inputs: query (unused — cancels in softmax), value, attention_mask
    const float* value = (const float*)d_in[1];
    const int*   mask  = (const int*)d_in[2];
    float* out = (float*)d_out;

    // workspace layout (~48.03 MB):
    unsigned short* Vt = (unsigned short*)d_ws;                       // B*D*K bf16 = 16 MB
    unsigned short* Wb = Vt + (size_t)BB * DD * KK;                   // B*Q*K bf16 = 32 MB
    float* s = (float*)(Wb + (size_t)BB * QQ * KK);                   // B*K fp32 raw row sums

    float* ctx  = out;                              // (B,Q,D)
    float* wout = out + (size_t)BB * QQ * DD;       // (B,Q,K)

    hipMemsetAsync(s, 0, (size_t)BB * KK * sizeof(float), stream);
    transpose_sum<<<BB * 512, 256, 0, stream>>>(value, Vt, s);
    weights_k<<<(BB * QQ) / 4, 256, 0, stream>>>(mask, s, wout, Wb);
    gemm_ctx<<<BB * 128, 256, 0, stream>>>(Wb, Vt, ctx);
}